// Round 1
// baseline (215.140 us; speedup 1.0000x reference)
//
#include <hip/hip_runtime.h>

// Problem constants
#define BB 4
#define NN 1024
#define FF 512
#define HH 8
#define DD 64
#define EE 16

typedef unsigned short u16;
typedef __attribute__((ext_vector_type(8))) short     bf16x8;
typedef __attribute__((ext_vector_type(8))) unsigned short u16x8;
typedef __attribute__((ext_vector_type(4))) float     f32x4;

#define MFMA(a,b,c) __builtin_amdgcn_mfma_f32_16x16x32_bf16((a),(b),(c),0,0,0)

static __device__ __forceinline__ u16 f2bf(float f){
  unsigned u = __float_as_uint(f);
  unsigned r = (u + 0x7FFFu + ((u >> 16) & 1u)) >> 16;   // RNE
  return (u16)r;
}
static __device__ __forceinline__ float bf2f(u16 h){
  return __uint_as_float(((unsigned)h) << 16);
}
static __device__ __forceinline__ void gld16(const void* g, void* l){
  __builtin_amdgcn_global_load_lds((const __attribute__((address_space(1))) unsigned int*)g,
                                   (__attribute__((address_space(3))) unsigned int*)l, 16, 0, 0);
}

// ---------------------------------------------------------------------------
// K0: transpose + hi/lo-split weights.
//  [Wq|Wk|Wv] (512f x 1536c fp32) -> WhT/WlT [c=1536][f=512] bf16
//  Wo (512f x 512c)               -> WoT [c=512][f=512] bf16 (hi only)
__global__ __launch_bounds__(256) void k_wsplit(
    const float* __restrict__ Wq, const float* __restrict__ Wk,
    const float* __restrict__ Wv, const float* __restrict__ Wo,
    u16* __restrict__ WhT, u16* __restrict__ WlT, u16* __restrict__ WoT){
  __shared__ float tile[32][33];
  int bid = blockIdx.x, t = threadIdx.x;
  int isA = bid < 768;
  int tb  = isA ? bid : bid - 768;
  int nct = isA ? 48 : 16;
  int ct = tb % nct, ft = tb / nct;
  int c0 = ct * 32, f0 = ft * 32;
  #pragma unroll
  for (int r4 = 0; r4 < 4; r4++){
    int fl = (t >> 5) * 4 + r4, cl = t & 31;
    int f = f0 + fl, c = c0 + cl;
    float v;
    if (isA){
      const float* W = (c < 512) ? Wq : ((c < 1024) ? Wk : Wv);
      v = W[f * 512 + (c & 511)];
    } else {
      v = Wo[f * 512 + c];
    }
    tile[fl][cl] = v;
  }
  __syncthreads();
  #pragma unroll
  for (int r4 = 0; r4 < 4; r4++){
    int cl = (t >> 5) * 4 + r4, fl = t & 31;
    float v = tile[fl][cl];
    int c = c0 + cl, f = f0 + fl;
    if (isA){
      u16 hi = f2bf(v);
      WhT[c * 512 + f] = hi;
      WlT[c * 512 + f] = f2bf(v - bf2f(hi));
    } else {
      WoT[c * 512 + f] = f2bf(v);
    }
  }
}

// ---------------------------------------------------------------------------
// K1: LayerNorm (fp32) -> r split into hi/lo bf16. One wave per row.
__global__ __launch_bounds__(256) void k_ln(
    const float* __restrict__ x, const float* __restrict__ gamma,
    const float* __restrict__ beta, u16* __restrict__ rh, u16* __restrict__ rl){
  int row  = blockIdx.x * 4 + (threadIdx.x >> 6);
  int lane = threadIdx.x & 63;
  const float* px = x + (size_t)row * 512 + lane * 8;
  float4 a = *(const float4*)px;
  float4 b = *(const float4*)(px + 4);
  float v[8] = {a.x,a.y,a.z,a.w,b.x,b.y,b.z,b.w};
  float s = 0.f, q = 0.f;
  #pragma unroll
  for (int j = 0; j < 8; j++){ s += v[j]; q += v[j]*v[j]; }
  #pragma unroll
  for (int m = 1; m < 64; m <<= 1){ s += __shfl_xor(s, m, 64); q += __shfl_xor(q, m, 64); }
  float mean = s * (1.f/512.f);
  float var  = q * (1.f/512.f) - mean * mean;
  float rstd = rsqrtf(var + 1e-5f);
  float4 ga = *(const float4*)(gamma + lane*8);
  float4 gb = *(const float4*)(gamma + lane*8 + 4);
  float4 b0 = *(const float4*)(beta  + lane*8);
  float4 b1 = *(const float4*)(beta  + lane*8 + 4);
  float gs[8] = {ga.x,ga.y,ga.z,ga.w,gb.x,gb.y,gb.z,gb.w};
  float bs[8] = {b0.x,b0.y,b0.z,b0.w,b1.x,b1.y,b1.z,b1.w};
  u16x8 hv, lv;
  #pragma unroll
  for (int j = 0; j < 8; j++){
    float r = (v[j] - mean) * rstd * gs[j] + bs[j];
    u16 hi = f2bf(r);
    hv[j] = hi;
    lv[j] = f2bf(r - bf2f(hi));
  }
  *(u16x8*)(rh + (size_t)row * 512 + lane * 8) = hv;
  *(u16x8*)(rl + (size_t)row * 512 + lane * 8) = lv;
}

// ---------------------------------------------------------------------------
// K2: QKV projection GEMM, split-3 (rh@Wh + rh@Wl + rl@Wh), 128x128 tile BK=32.
// A = r [4096][512] (hi/lo), B = WT [1536][512] (hi/lo, row-major = B^T form).
// Epilogue: q,k -> hi/lo [b][h][n][64]; v -> transposed [b][h][64][n] bf16.
__global__ __launch_bounds__(256) void k_qkv(
    const u16* __restrict__ rh, const u16* __restrict__ rl,
    const u16* __restrict__ WhT, const u16* __restrict__ WlT,
    u16* __restrict__ qh, u16* __restrict__ ql,
    u16* __restrict__ kh, u16* __restrict__ kl, u16* __restrict__ vT){
  __shared__ u16 Ah[128*32], Al[128*32], Bh[128*32], Bl[128*32];
  int bid = blockIdx.x;
  int mt = bid & 31, nt = bid >> 5;       // 32 m-tiles x 12 n-tiles
  int m0 = mt << 7,  n0 = nt << 7;
  int t = threadIdx.x, lane = t & 63, w = t >> 6;
  int wm = (w >> 1) << 6, wn = (w & 1) << 6;
  int fr = lane & 15, g = lane >> 4;
  f32x4 acc[4][4];
  #pragma unroll
  for (int i = 0; i < 4; i++)
    #pragma unroll
    for (int j = 0; j < 4; j++) acc[i][j] = (f32x4){0.f,0.f,0.f,0.f};

  for (int k0 = 0; k0 < 512; k0 += 32){
    #pragma unroll
    for (int q = 0; q < 2; q++){
      int c = ((q << 2) + w) * 64 + lane;   // chunk id, 16B each
      int row = c >> 2, part = c & 3;
      int ldso = ((q << 2) + w) * 512;      // u16 units, wave-uniform
      gld16(rh  + (size_t)(m0+row)*512 + k0 + part*8, &Ah[ldso]);
      gld16(rl  + (size_t)(m0+row)*512 + k0 + part*8, &Al[ldso]);
      gld16(WhT + (size_t)(n0+row)*512 + k0 + part*8, &Bh[ldso]);
      gld16(WlT + (size_t)(n0+row)*512 + k0 + part*8, &Bl[ldso]);
    }
    __syncthreads();
    bf16x8 a_h[4], a_l[4], b_h[4], b_l[4];
    #pragma unroll
    for (int mi = 0; mi < 4; mi++){
      int off = (wm + mi*16 + fr)*32 + g*8;
      a_h[mi] = *(const bf16x8*)&Ah[off];
      a_l[mi] = *(const bf16x8*)&Al[off];
    }
    #pragma unroll
    for (int ni = 0; ni < 4; ni++){
      int off = (wn + ni*16 + fr)*32 + g*8;
      b_h[ni] = *(const bf16x8*)&Bh[off];
      b_l[ni] = *(const bf16x8*)&Bl[off];
    }
    #pragma unroll
    for (int mi = 0; mi < 4; mi++)
      #pragma unroll
      for (int ni = 0; ni < 4; ni++){
        acc[mi][ni] = MFMA(a_h[mi], b_h[ni], acc[mi][ni]);
        acc[mi][ni] = MFMA(a_h[mi], b_l[ni], acc[mi][ni]);
        acc[mi][ni] = MFMA(a_l[mi], b_h[ni], acc[mi][ni]);
      }
    __syncthreads();
  }
  #pragma unroll
  for (int mi = 0; mi < 4; mi++)
    #pragma unroll
    for (int ni = 0; ni < 4; ni++)
      #pragma unroll
      for (int r = 0; r < 4; r++){
        int gm = m0 + wm + mi*16 + g*4 + r;
        int gc = n0 + wn + ni*16 + fr;
        float vv = acc[mi][ni][r];
        int b = gm >> 10, i = gm & 1023;
        int mat = gc >> 9, h = (gc >> 6) & 7, d = gc & 63;
        size_t idx = ((size_t)((b << 3) + h) * 1024 + i) * 64 + d;
        if (mat == 0){
          u16 hi = f2bf(vv); qh[idx] = hi; ql[idx] = f2bf(vv - bf2f(hi));
        } else if (mat == 1){
          u16 hi = f2bf(vv); kh[idx] = hi; kl[idx] = f2bf(vv - bf2f(hi));
        } else {
          vT[((size_t)((b << 3) + h) * 64 + d) * 1024 + i] = f2bf(vv);
        }
      }
}

// ---------------------------------------------------------------------------
// K3: fused attention. 256 blocks = (b, i-tile of 16). 512 thr = 8 waves = 8 heads.
// Per 32-wide j-tile: cooperative edge->bias in LDS; per head 3-pass QK MFMA,
// online softmax over all j (mask applied post-softmax in numerator only), PV MFMA.
__global__ __launch_bounds__(512) void k_attn(
    const float* __restrict__ edge, const float* __restrict__ mask,
    const float* __restrict__ We,
    const u16* __restrict__ qh, const u16* __restrict__ ql,
    const u16* __restrict__ kh, const u16* __restrict__ kl,
    const u16* __restrict__ vT, u16* __restrict__ AO){
  __shared__ float We_s[128];                 // [e][h]
  __shared__ float bias_s[8][16*33];          // [h][i*33+j]
  __shared__ float mask_s[16*33];             // [i*33+j]
  __shared__ u16   pm_s[8][16*40];            // per-wave [i][40] bf16 (pad 32->40)

  int bid = blockIdx.x;
  int b = bid >> 6, i0 = (bid & 63) << 4;
  int t = threadIdx.x, lane = t & 63, w = t >> 6;   // w = head
  int fr = lane & 15, g = lane >> 4;
  if (t < 128) We_s[t] = We[t];

  // Q fragments (rows i0..i0+15, all 64 d), hi/lo
  size_t qb = ((size_t)((b << 3) + w) * 1024 + i0 + fr) * 64 + g * 8;
  bf16x8 qfh0 = *(const bf16x8*)(qh + qb);
  bf16x8 qfh1 = *(const bf16x8*)(qh + qb + 32);
  bf16x8 qfl0 = *(const bf16x8*)(ql + qb);
  bf16x8 qfl1 = *(const bf16x8*)(ql + qb + 32);

  f32x4 oacc[4];
  #pragma unroll
  for (int vf = 0; vf < 4; vf++) oacc[vf] = (f32x4){0.f,0.f,0.f,0.f};
  float mrun[4], den[4];
  #pragma unroll
  for (int r = 0; r < 4; r++){ mrun[r] = -3e38f; den[r] = 0.f; }

  int pi = t >> 5, pj = t & 31;               // this thread's (i,j) pair for bias
  const float* ebase = edge + (size_t)(b*1024 + i0 + pi) * 16384 + (size_t)pj * 16;
  const float* mbase = mask + (size_t)(b*1024 + i0 + pi) * 1024 + pj;
  __syncthreads();

  // prologue: issue edge+mask loads for tile 0
  float4 e0 = *(const float4*)(ebase);
  float4 e1 = *(const float4*)(ebase + 4);
  float4 e2 = *(const float4*)(ebase + 8);
  float4 e3 = *(const float4*)(ebase + 12);
  float  mval = *mbase;

  #pragma unroll 1
  for (int jt = 0; jt < 32; jt++){
    int j0 = jt << 5;
    // bias for this tile from regs
    float ef[16] = {e0.x,e0.y,e0.z,e0.w, e1.x,e1.y,e1.z,e1.w,
                    e2.x,e2.y,e2.z,e2.w, e3.x,e3.y,e3.z,e3.w};
    float bias[8] = {0.f,0.f,0.f,0.f,0.f,0.f,0.f,0.f};
    #pragma unroll
    for (int e = 0; e < 16; e++){
      float ev = ef[e];
      #pragma unroll
      for (int h = 0; h < 8; h++) bias[h] += ev * We_s[e*8 + h];
    }
    #pragma unroll
    for (int h = 0; h < 8; h++) bias_s[h][pi*33 + pj] = bias[h];
    mask_s[pi*33 + pj] = mval;
    __syncthreads();

    // prefetch next tile's edge (completes by end-of-loop barrier)
    if (jt < 31){
      const float* ep = ebase + (size_t)(j0 + 32) * 16;
      e0 = *(const float4*)(ep);
      e1 = *(const float4*)(ep + 4);
      e2 = *(const float4*)(ep + 8);
      e3 = *(const float4*)(ep + 12);
      mval = mbase[j0 + 32];
    }

    // K fragments for this head (j0..j0+31, hi/lo)
    size_t kb0 = ((size_t)((b << 3) + w) * 1024 + j0 + fr) * 64 + g * 8;
    size_t kb1 = kb0 + 16 * 64;
    bf16x8 kfh00 = *(const bf16x8*)(kh + kb0);
    bf16x8 kfh01 = *(const bf16x8*)(kh + kb0 + 32);
    bf16x8 kfh10 = *(const bf16x8*)(kh + kb1);
    bf16x8 kfh11 = *(const bf16x8*)(kh + kb1 + 32);
    bf16x8 kfl00 = *(const bf16x8*)(kl + kb0);
    bf16x8 kfl01 = *(const bf16x8*)(kl + kb0 + 32);
    bf16x8 kfl10 = *(const bf16x8*)(kl + kb1);
    bf16x8 kfl11 = *(const bf16x8*)(kl + kb1 + 32);

    f32x4 lg0 = (f32x4){0.f,0.f,0.f,0.f};
    f32x4 lg1 = (f32x4){0.f,0.f,0.f,0.f};
    lg0 = MFMA(qfh0, kfh00, lg0); lg0 = MFMA(qfh1, kfh01, lg0);
    lg0 = MFMA(qfh0, kfl00, lg0); lg0 = MFMA(qfh1, kfl01, lg0);
    lg0 = MFMA(qfl0, kfh00, lg0); lg0 = MFMA(qfl1, kfh01, lg0);
    lg1 = MFMA(qfh0, kfh10, lg1); lg1 = MFMA(qfh1, kfh11, lg1);
    lg1 = MFMA(qfh0, kfl10, lg1); lg1 = MFMA(qfh1, kfl11, lg1);
    lg1 = MFMA(qfl0, kfh10, lg1); lg1 = MFMA(qfl1, kfh11, lg1);

    float tm[4];
    #pragma unroll
    for (int r = 0; r < 4; r++){
      int row = g*4 + r;
      lg0[r] += bias_s[w][row*33 + fr];
      lg1[r] += bias_s[w][row*33 + 16 + fr];
      tm[r] = fmaxf(lg0[r], lg1[r]);
    }
    #pragma unroll
    for (int mk = 1; mk < 16; mk <<= 1){
      #pragma unroll
      for (int r = 0; r < 4; r++) tm[r] = fmaxf(tm[r], __shfl_xor(tm[r], mk, 16));
    }
    float p0[4], p1[4], scl[4], ps[4];
    #pragma unroll
    for (int r = 0; r < 4; r++){
      float nm = fmaxf(mrun[r], tm[r]);
      scl[r] = exp2f((mrun[r] - nm) * 1.44269504089f);
      mrun[r] = nm;
      p0[r] = exp2f((lg0[r] - nm) * 1.44269504089f);
      p1[r] = exp2f((lg1[r] - nm) * 1.44269504089f);
      ps[r] = p0[r] + p1[r];
    }
    #pragma unroll
    for (int mk = 1; mk < 16; mk <<= 1){
      #pragma unroll
      for (int r = 0; r < 4; r++) ps[r] += __shfl_xor(ps[r], mk, 16);
    }
    #pragma unroll
    for (int r = 0; r < 4; r++) den[r] = den[r] * scl[r] + ps[r];
    #pragma unroll
    for (int vf = 0; vf < 4; vf++)
      #pragma unroll
      for (int r = 0; r < 4; r++) oacc[vf][r] *= scl[r];

    // masked P -> bf16 -> LDS (C-layout scatter), then A-frag read
    #pragma unroll
    for (int r = 0; r < 4; r++){
      int row = g*4 + r;
      pm_s[w][row*40 + fr]      = f2bf(p0[r] * mask_s[row*33 + fr]);
      pm_s[w][row*40 + 16 + fr] = f2bf(p1[r] * mask_s[row*33 + 16 + fr]);
    }
    asm volatile("s_waitcnt lgkmcnt(0)" ::: "memory");
    bf16x8 pa = *(const bf16x8*)&pm_s[w][fr*40 + g*8];
    #pragma unroll
    for (int vf = 0; vf < 4; vf++){
      const u16* vp = vT + ((size_t)((b << 3) + w) * 64 + vf*16 + fr) * 1024 + j0 + g*8;
      bf16x8 vfr = *(const bf16x8*)vp;
      oacc[vf] = MFMA(pa, vfr, oacc[vf]);
    }
    __syncthreads();
  }

  float id[4];
  #pragma unroll
  for (int r = 0; r < 4; r++) id[r] = 0.125f / den[r];   // fold in 1/sqrt(D)
  #pragma unroll
  for (int vf = 0; vf < 4; vf++)
    #pragma unroll
    for (int r = 0; r < 4; r++){
      int row = g*4 + r, v = vf*16 + fr;
      AO[((size_t)(b*1024 + i0 + row)) * 512 + w*64 + v] = f2bf(oacc[vf][r] * id[r]);
    }
}

// ---------------------------------------------------------------------------
// K5: out = AO @ Wo + residual. Single-pass bf16, 64x128 tile, BK=32.
__global__ __launch_bounds__(256) void k_out(
    const u16* __restrict__ AO, const u16* __restrict__ WoT,
    const float* __restrict__ x, float* __restrict__ out){
  __shared__ u16 As[64*32], Bs[128*32];
  int bid = blockIdx.x;
  int mt = bid & 63, nt = bid >> 6;     // 64 x 4
  int m0 = mt << 6, n0 = nt << 7;
  int t = threadIdx.x, lane = t & 63, w = t >> 6;
  int wm = (w >> 1) << 5, wn = (w & 1) << 6;
  int fr = lane & 15, g = lane >> 4;
  f32x4 acc[2][4];
  #pragma unroll
  for (int i = 0; i < 2; i++)
    #pragma unroll
    for (int j = 0; j < 4; j++) acc[i][j] = (f32x4){0.f,0.f,0.f,0.f};

  for (int k0 = 0; k0 < 512; k0 += 32){
    {
      int row = t >> 2, part = t & 3;
      gld16(AO + (size_t)(m0+row)*512 + k0 + part*8, &As[w*512]);
    }
    #pragma unroll
    for (int q = 0; q < 2; q++){
      int c = ((q << 2) + w) * 64 + lane;
      int row = c >> 2, part = c & 3;
      gld16(WoT + (size_t)(n0+row)*512 + k0 + part*8, &Bs[((q<<2)+w)*512]);
    }
    __syncthreads();
    bf16x8 af[2], bf_[4];
    #pragma unroll
    for (int mi = 0; mi < 2; mi++) af[mi]  = *(const bf16x8*)&As[(wm + mi*16 + fr)*32 + g*8];
    #pragma unroll
    for (int ni = 0; ni < 4; ni++) bf_[ni] = *(const bf16x8*)&Bs[(wn + ni*16 + fr)*32 + g*8];
    #pragma unroll
    for (int mi = 0; mi < 2; mi++)
      #pragma unroll
      for (int ni = 0; ni < 4; ni++)
        acc[mi][ni] = MFMA(af[mi], bf_[ni], acc[mi][ni]);
    __syncthreads();
  }
  #pragma unroll
  for (int mi = 0; mi < 2; mi++)
    #pragma unroll
    for (int ni = 0; ni < 4; ni++)
      #pragma unroll
      for (int r = 0; r < 4; r++){
        size_t gm = m0 + wm + mi*16 + g*4 + r;
        size_t gn = n0 + wn + ni*16 + fr;
        out[gm*512 + gn] = acc[mi][ni][r] + x[gm*512 + gn];
      }
}

// ---------------------------------------------------------------------------
extern "C" void kernel_launch(void* const* d_in, const int* in_sizes, int n_in,
                              void* d_out, int out_size, void* d_ws, size_t ws_size,
                              hipStream_t stream){
  const float* xin   = (const float*)d_in[0];
  const float* edge  = (const float*)d_in[1];
  const float* mask  = (const float*)d_in[2];
  const float* gamma = (const float*)d_in[3];
  const float* beta  = (const float*)d_in[4];
  const float* Wq    = (const float*)d_in[5];
  const float* Wk    = (const float*)d_in[6];
  const float* Wv    = (const float*)d_in[7];
  const float* We    = (const float*)d_in[8];
  const float* Wo    = (const float*)d_in[9];
  float* out = (float*)d_out;

  u16* p   = (u16*)d_ws;
  u16* WhT = p;                 p += 1536*512;
  u16* WlT = p;                 p += 1536*512;
  u16* WoT = p;                 p += 512*512;
  u16* rh  = p;                 p += 4096*512;
  u16* rl  = p;                 p += 4096*512;
  u16* qh  = p;                 p += 2097152;
  u16* ql  = p;                 p += 2097152;
  u16* kh  = p;                 p += 2097152;
  u16* kl  = p;                 p += 2097152;
  u16* vT  = p;                 p += 2097152;
  u16* AO  = p;                 p += 2097152;

  k_wsplit<<<1024, 256, 0, stream>>>(Wq, Wk, Wv, Wo, WhT, WlT, WoT);
  k_ln    <<<1024, 256, 0, stream>>>(xin, gamma, beta, rh, rl);
  k_qkv   <<<384,  256, 0, stream>>>(rh, rl, WhT, WlT, qh, ql, kh, kl, vT);
  k_attn  <<<256,  512, 0, stream>>>(edge, mask, We, qh, ql, kh, kl, vT, AO);
  k_out   <<<256,  256, 0, stream>>>(AO, WoT, xin, out);
}